// Round 13
// baseline (271.794 us; speedup 1.0000x reference)
//
#include <hip/hip_runtime.h>
#include <stdint.h>

#define DD 2048
#define SS 2048
#define NB 2
#define NH 16
#define HDIM 128
#define MM (NB*SS)   // 4096 rows

typedef __attribute__((ext_vector_type(8))) short bf16x8;
typedef __attribute__((ext_vector_type(4))) float f32x4;
typedef __attribute__((ext_vector_type(4))) ushort u16x4;

__device__ __forceinline__ float fast_exp2(float x) {
  return __builtin_amdgcn_exp2f(x);   // v_exp_f32 (2^x natively)
}

__device__ __forceinline__ ushort f2bf(float f) {
  union { float f; uint32_t u; } v; v.f = f;
  uint32_t u = v.u;
  return (ushort)((u + 0x7fffu + ((u >> 16) & 1u)) >> 16);
}

__device__ __forceinline__ void gld_lds16(const ushort* g, ushort* l) {
  __builtin_amdgcn_global_load_lds(
      (const __attribute__((address_space(1))) void*)g,
      (__attribute__((address_space(3))) void*)l, 16, 0, 0);
}

// ---------------- fp32 -> bf16 conversion of x and the 4 weights -------------
__global__ __launch_bounds__(256) void cvt_all(
    const float* __restrict__ x, const float* __restrict__ wq,
    const float* __restrict__ wk, const float* __restrict__ wv,
    const float* __restrict__ wo, ushort* __restrict__ dst)
{
  int i8 = blockIdx.x * 256 + threadIdx.x;   // one 8-float chunk per thread
  const int X8 = MM * DD / 8;                // 1,048,576
  const int W8 = DD * DD / 8;                // 524,288
  const float* src; int off;
  if (i8 < X8)            { src = x;  off = i8; }
  else if (i8 < X8 +   W8){ src = wq; off = i8 - X8; }
  else if (i8 < X8 + 2*W8){ src = wk; off = i8 - (X8 +   W8); }
  else if (i8 < X8 + 3*W8){ src = wv; off = i8 - (X8 + 2*W8); }
  else                    { src = wo; off = i8 - (X8 + 3*W8); }
  const float4* p = (const float4*)src;
  float4 a = p[(long)off*2], b = p[(long)off*2 + 1];
  bf16x8 o;
  o[0]=(short)f2bf(a.x); o[1]=(short)f2bf(a.y); o[2]=(short)f2bf(a.z); o[3]=(short)f2bf(a.w);
  o[4]=(short)f2bf(b.x); o[5]=(short)f2bf(b.y); o[6]=(short)f2bf(b.z); o[7]=(short)f2bf(b.w);
  *(bf16x8*)(dst + (long)i8*8) = o;
}

// ======== m201-style 8-phase QKV GEMM: 256x256, BK=64, 8 waves, dbuf ========
// 2 K-tiles/iteration, 8 phases; one half-tile (16KB, 2 gld/thread) staged per
// phase into the half provably freed by an earlier phase's end-barrier (each
// wave reads ONLY its A-half wr and B-half wcn>>1). Counted vmcnt(4) at P4/P8
// = 2 newest half-stages outstanding, all older landed; drain only in tail.
__global__ __launch_bounds__(512, 2) void gemm8p(
    const ushort* __restrict__ A, const ushort* __restrict__ Bt,
    ushort* __restrict__ Qo, ushort* __restrict__ Ko, ushort* __restrict__ Vt)
{
  __shared__ char lds[131072];   // 2 bufs x (A 32KB + B 32KB)
  const int t = threadIdx.x;
  const int bid = blockIdx.x;             // 384 = 8 XCD x 48
  const int xcd = bid & 7, local = bid >> 3;
  const int bm = local / 3;               // 0..15
  const int bn = xcd * 3 + (local - bm*3);// 0..23 (3-wide B panel per XCD L2)
  const int lane = t & 63, w = t >> 6;
  const int wr = w >> 2;                  // 0..1 : A-half (128 rows)
  const int wcn = w & 3;                  // 0..3 : 64-col group
  const int lr = lane & 15, lg = lane >> 4;

  // staging: per half-tile 1024 chunks (16B); thread t owns chunks t, 512+t.
  // chunk c: row c>>3, slot c&7 holds global chunk (c&7)^((c>>3)&7).
  const int o0 = (t >> 3) * DD + (((t & 7) ^ ((t >> 3) & 7)) * 8);
  const ushort* Ab = A  + (long)(bm*256) * DD;
  const ushort* Bb = Bt + (long)(bn*256) * DD;

  // LDS byte map: buf b: A-half h @ b*65536 + h*16384; B-half h @ +32768.
#define STG(gbase, KT, HALF, LBYTE) do {                                   \
    const ushort* g_ = (gbase) + (KT)*64 + (HALF)*128*DD + o0;             \
    ushort* l_ = (ushort*)(lds + (LBYTE)) + t*8;                           \
    gld_lds16(g_, l_);                                                     \
    gld_lds16(g_ + 64*DD, l_ + 4096); } while (0)
#define LDA(dst, M, ks, buf) { int r_ = (M)*16 + lr;                       \
    (dst) = *(const bf16x8*)(lds + (buf)*65536 + wr*16384 + r_*128 +       \
              ((((ks)*4+lg) ^ (r_ & 7)) * 16)); }
#define LDB(dst, n, ks, buf) { int r_ = (wcn & 1)*64 + (n)*16 + lr;        \
    (dst) = *(const bf16x8*)(lds + (buf)*65536 + 32768 + (wcn>>1)*16384 +  \
              r_*128 + ((((ks)*4+lg) ^ (r_ & 7)) * 16)); }
#define MFMA16(AV, BV, MB, NBASE) do {                                     \
    __builtin_amdgcn_s_setprio(1);                                         \
    _Pragma("unroll") for (int ks = 0; ks < 2; ++ks)                       \
    _Pragma("unroll") for (int m = 0; m < 4; ++m)                          \
    _Pragma("unroll") for (int n = 0; n < 2; ++n)                          \
      acc[(MB)+m][(NBASE)+n] = __builtin_amdgcn_mfma_f32_16x16x32_bf16(    \
          AV[m][ks], BV[n][ks], acc[(MB)+m][(NBASE)+n], 0, 0, 0);          \
    __builtin_amdgcn_s_setprio(0); } while (0)
#define SB  __builtin_amdgcn_sched_barrier(0)
#define BAR __builtin_amdgcn_s_barrier()
#define LGKM0 asm volatile("s_waitcnt lgkmcnt(0)" ::: "memory")
#define VM4 asm volatile("s_waitcnt vmcnt(4)" ::: "memory")
#define VM0 asm volatile("s_waitcnt vmcnt(0)" ::: "memory")

  f32x4 acc[8][4] = {};
  const int T = 32;                       // K-tiles (BK=64)

  // prologue: tile0 all 4 halves -> buf0; tile1 A halves -> buf1
  STG(Ab, 0, 0, 0);      STG(Ab, 0, 1, 16384);
  STG(Bb, 0, 0, 32768);  STG(Bb, 0, 1, 49152);
  STG(Ab, 1, 0, 65536);  STG(Ab, 1, 1, 65536+16384);
  VM4;                                    // tile0's 4 halves landed
  SB; BAR; SB;

  for (int i = 0; i < 16; ++i) {
    const int a = 2*i, tb = 2*i + 1;
    const bool st0 = (a + 2 < T);         // stage tile a+2 -> buf0
    const bool st1 = (tb + 2 < T);        // stage tile tb+2 -> buf1
    bf16x8 af0[4][2], af1[4][2], bf0[2][2], bf1[2][2];

    // ================== tile a (buf0) ==================
    // P1: Q00 | stage tb.Bh0 -> buf1 (read at P5; landed by P4's vmcnt)
#pragma unroll
    for (int ks = 0; ks < 2; ++ks) {
      LDA(af0[0][ks],0,ks,0); LDA(af0[1][ks],1,ks,0);
      LDA(af0[2][ks],2,ks,0); LDA(af0[3][ks],3,ks,0);
      LDB(bf0[0][ks],0,ks,0); LDB(bf0[1][ks],1,ks,0);
    }
    STG(Bb, tb, 0, 65536+32768);
    SB; BAR; LGKM0; SB;
    MFMA16(af0, bf0, 0, 0);
    SB; BAR; SB;
    // P2: Q10 | stage tb.Bh1
#pragma unroll
    for (int ks = 0; ks < 2; ++ks) {
      LDA(af1[0][ks],4,ks,0); LDA(af1[1][ks],5,ks,0);
      LDA(af1[2][ks],6,ks,0); LDA(af1[3][ks],7,ks,0);
    }
    STG(Bb, tb, 1, 65536+49152);
    SB; BAR; LGKM0; SB;
    MFMA16(af1, bf0, 4, 0);
    SB; BAR; SB;
    // P3: Q11 | stage (a+2).Ah0 -> buf0 (A-halves free after P2-end)
#pragma unroll
    for (int ks = 0; ks < 2; ++ks) {
      LDB(bf1[0][ks],2,ks,0); LDB(bf1[1][ks],3,ks,0);
    }
    if (st0) STG(Ab, a+2, 0, 0);
    SB; BAR; LGKM0; SB;
    MFMA16(af1, bf1, 4, 2);
    SB; BAR; SB;
    // P4: Q01 | stage (a+2).Ah1; counted wait: tile tb fully landed
    if (st0) { STG(Ab, a+2, 1, 16384); VM4; } else { VM0; }
    SB; BAR; SB;
    MFMA16(af0, bf1, 0, 2);
    SB; BAR; SB;

    // ================== tile tb (buf1) ==================
    // P5: Q00 | stage (a+2).Bh0 -> buf0 (B-halves free after P3-end)
#pragma unroll
    for (int ks = 0; ks < 2; ++ks) {
      LDA(af0[0][ks],0,ks,1); LDA(af0[1][ks],1,ks,1);
      LDA(af0[2][ks],2,ks,1); LDA(af0[3][ks],3,ks,1);
      LDB(bf0[0][ks],0,ks,1); LDB(bf0[1][ks],1,ks,1);
    }
    if (st0) STG(Bb, a+2, 0, 32768);
    SB; BAR; LGKM0; SB;
    MFMA16(af0, bf0, 0, 0);
    SB; BAR; SB;
    // P6: Q10 | stage (a+2).Bh1
#pragma unroll
    for (int ks = 0; ks < 2; ++ks) {
      LDA(af1[0][ks],4,ks,1); LDA(af1[1][ks],5,ks,1);
      LDA(af1[2][ks],6,ks,1); LDA(af1[3][ks],7,ks,1);
    }
    if (st0) STG(Bb, a+2, 1, 49152);
    SB; BAR; LGKM0; SB;
    MFMA16(af1, bf0, 4, 0);
    SB; BAR; SB;
    // P7: Q11 | stage (tb+2).Ah0 -> buf1 (buf1 A-halves free after P6-end)
#pragma unroll
    for (int ks = 0; ks < 2; ++ks) {
      LDB(bf1[0][ks],2,ks,1); LDB(bf1[1][ks],3,ks,1);
    }
    if (st1) STG(Ab, tb+2, 0, 65536);
    SB; BAR; LGKM0; SB;
    MFMA16(af1, bf1, 4, 2);
    SB; BAR; SB;
    // P8: Q01 | stage (tb+2).Ah1; counted wait: tile a+2 fully landed
    if (st1) { STG(Ab, tb+2, 1, 65536+16384); VM4; } else { VM0; }
    SB; BAR; SB;
    MFMA16(af0, bf1, 0, 2);
    SB; BAR; SB;
  }
#undef STG
#undef LDA
#undef LDB
#undef MFMA16
#undef SB
#undef BAR
#undef LGKM0
#undef VM4
#undef VM0

  // epilogue: C/D layout col=lane&15, row=(lane>>4)*4+j  (R7-verified mapping)
  const int crb = bm*256 + wr*128 + lg*4;
  const int region = bn >> 3;              // 0=Q, 1=K, 2=V (8 bn-tiles each)
  const int ccb = (bn & 7)*256 + wcn*64 + lr;
  if (region < 2) {
    const float scale = (region == 0) ? (0.08838834764831845f * 1.4426950408889634f) : 1.0f;
    ushort* C = (region == 0) ? Qo : Ko;
#pragma unroll
    for (int m = 0; m < 8; ++m)
#pragma unroll
      for (int n = 0; n < 4; ++n)
#pragma unroll
        for (int j = 0; j < 4; ++j)
          C[(long)(crb + m*16 + j) * DD + (ccb + n*16)] = f2bf(acc[m][n][j] * scale);
  } else {
    // V transposed: Vt[(b*NH+h)*HDIM + d][s]; 4 j-rows = 4 contiguous s
#pragma unroll
    for (int m = 0; m < 8; ++m) {
      int sg = crb + m*16;
      int vb = sg >> 11, s2 = sg & 2047;
#pragma unroll
      for (int n = 0; n < 4; ++n) {
        int colv = ccb + n*16;
        int h2 = colv >> 7, d2 = colv & 127;
        u16x4 pk;
        pk[0] = f2bf(acc[m][n][0]); pk[1] = f2bf(acc[m][n][1]);
        pk[2] = f2bf(acc[m][n][2]); pk[3] = f2bf(acc[m][n][3]);
        *(u16x4*)(Vt + ((long)((vb*NH + h2)*HDIM + d2)) * SS + s2) = pk;
      }
    }
  }
}

// ---- O-proj GEMM: 256x128, BK=32, 4 waves, TRIPLE buffer (R9-verified) -----
template<int MODE>
__global__ __launch_bounds__(256, 2) void gemm_tri(
    const ushort* __restrict__ A, const ushort* __restrict__ Bt,
    float* __restrict__ Cf)
{
  __shared__ ushort lds[3 * 12288];          // 3 x 24 KB = 72 KB
  const int t = threadIdx.x;
  const int bid = blockIdx.x;
  const int xcd = bid & 7, local = bid >> 3;
  const int NBX = 2;
  const int bm = local / NBX;
  const int bn = xcd * NBX + (local - bm * NBX);
  const int lane = t & 63, w = t >> 6;
  const int wr = w >> 1, wcn = w & 1;        // 2M x 2N; per-wave 128x64
  const int lr = lane & 15, lg = lane >> 4;

  int aoff[4], boff[2];
#pragma unroll
  for (int i = 0; i < 4; ++i) {
    int p = i*256 + t, ln = p >> 3, sr = (p & 7) ^ (ln & 7);
    aoff[i] = (2*ln + (sr >> 2)) * DD + (sr & 3) * 8;
  }
#pragma unroll
  for (int i = 0; i < 2; ++i) {
    int p = i*256 + t, ln = p >> 3, sr = (p & 7) ^ (ln & 7);
    boff[i] = (2*ln + (sr >> 2)) * DD + (sr & 3) * 8;
  }
  const ushort* Ab = A  + (long)(bm*256) * DD;
  const ushort* Bb = Bt + (long)(bn*128) * DD;

#define STG_A01(KT, BUF) do { const ushort* g_ = Ab + (KT)*32;             \
    ushort* l_ = lds + (BUF)*12288;                                        \
    gld_lds16(g_ + aoff[0], l_ + t*8);                                     \
    gld_lds16(g_ + aoff[1], l_ + (256 + t)*8); } while (0)
#define STG_A23(KT, BUF) do { const ushort* g_ = Ab + (KT)*32;             \
    ushort* l_ = lds + (BUF)*12288;                                        \
    gld_lds16(g_ + aoff[2], l_ + (512 + t)*8);                             \
    gld_lds16(g_ + aoff[3], l_ + (768 + t)*8); } while (0)
#define STG_B(KT, BUF)   do { const ushort* g_ = Bb + (KT)*32;             \
    ushort* l_ = lds + (BUF)*12288 + 8192;                                 \
    gld_lds16(g_ + boff[0], l_ + t*8);                                     \
    gld_lds16(g_ + boff[1], l_ + (256 + t)*8); } while (0)
#define LDA(dst, m) { int r_ = wr*128 + (m)*16 + lr; int ln_ = r_ >> 1;    \
    int sl_ = (lg + ((r_ & 1) << 2)) ^ (ln_ & 7);                          \
    (dst) = *(const bf16x8*)(cb + ln_*128 + sl_*16); }
#define LDB(dst, n) { int r_ = wcn*64 + (n)*16 + lr; int ln_ = r_ >> 1;    \
    int sl_ = (lg + ((r_ & 1) << 2)) ^ (ln_ & 7);                          \
    (dst) = *(const bf16x8*)(cb + 16384 + ln_*128 + sl_*16); }
#define MFMA42(AV, BV, MB, NB_) do {                                       \
    __builtin_amdgcn_s_setprio(1);                                         \
    _Pragma("unroll") for (int m = 0; m < 4; ++m)                          \
    _Pragma("unroll") for (int n = 0; n < 2; ++n)                          \
      acc[(MB)+m][(NB_)+n] = __builtin_amdgcn_mfma_f32_16x16x32_bf16(      \
          AV[m], BV[n], acc[(MB)+m][(NB_)+n], 0, 0, 0);                    \
    __builtin_amdgcn_s_setprio(0); } while (0)
#define SB  __builtin_amdgcn_sched_barrier(0)
#define BAR __builtin_amdgcn_s_barrier()
#define LGKM0 asm volatile("s_waitcnt lgkmcnt(0)" ::: "memory")

  f32x4 acc[8][4] = {};
  const int T = DD / 32;

  STG_A01(0, 0); STG_A23(0, 0); STG_B(0, 0);
  STG_A01(1, 1); STG_A23(1, 1); STG_B(1, 1);
  asm volatile("s_waitcnt vmcnt(6)" ::: "memory");
  SB; BAR; SB;

  for (int kt = 0; kt < T; ++kt) {
    const char* cb = (const char*)lds + (kt % 3) * 24576;
    const int bs = (kt + 2) % 3;
    const bool st = (kt + 2 < T);
    bf16x8 a03[4], a47[4], b01[2], b23[2];
    LDA(a03[0],0); LDA(a03[1],1); LDA(a03[2],2); LDA(a03[3],3);
    LDB(b01[0],0); LDB(b01[1],1);
    if (st) STG_A01(kt+2, bs);
    SB; BAR; LGKM0; SB;
    MFMA42(a03, b01, 0, 0);
    SB; BAR; SB;
    LDA(a47[0],4); LDA(a47[1],5); LDA(a47[2],6); LDA(a47[3],7);
    if (st) STG_A23(kt+2, bs);
    SB; BAR; LGKM0; SB;
    MFMA42(a47, b01, 4, 0);
    SB; BAR; SB;
    LDB(b23[0],2); LDB(b23[1],3);
    if (st) STG_B(kt+2, bs);
    SB; BAR; LGKM0; SB;
    MFMA42(a03, b23, 0, 2);
    SB; BAR; SB;
    if (st)              { asm volatile("s_waitcnt vmcnt(6)" ::: "memory"); }
    else if (kt + 1 < T) { asm volatile("s_waitcnt vmcnt(0)" ::: "memory"); }
    SB; BAR; SB;
    MFMA42(a47, b23, 4, 2);
    SB; BAR; SB;
  }
#undef STG_A01
#undef STG_A23
#undef STG_B
#undef LDA
#undef LDB
#undef MFMA42
#undef SB
#undef BAR
#undef LGKM0

  const int crb = bm*256 + wr*128 + lg*4;
  const int ccb = bn*128 + wcn*64 + lr;
#pragma unroll
  for (int m = 0; m < 8; ++m)
#pragma unroll
    for (int n = 0; n < 4; ++n)
#pragma unroll
      for (int j = 0; j < 4; ++j)
        Cf[(long)(crb + m*16 + j) * DD + (ccb + n*16)] = acc[m][n][j];
}

// ------------- causal flash attention: pipelined + pair-balanced -------------
// (unchanged from round 12 -- verified, < 115 us)
__global__ __launch_bounds__(512, 4) void attn_fwd(
    const ushort* __restrict__ Qb, const ushort* __restrict__ Kb,
    const ushort* __restrict__ Vtg, ushort* __restrict__ Ob)
{
  __shared__ ushort Ks[2][64*128];  // 2 x 16 KB, [k][d] XOR-swizzled chunks
  __shared__ ushort Vs[2][128*64];  // 2 x 16 KB, [d][k] XOR-swizzled chunks
  __shared__ ushort Ps[8*16*68];    // per-wave P [16][64], pad 68 (2-way)

  const int bid = blockIdx.x;       // 256 blocks: p(8) x bh(32)
  const int p = bid >> 5;           // 0..7
  const int bh = bid & 31;
  const int b = bh >> 4, h = bh & 15;
  const int t = threadIdx.x;
  const int lane = t & 63;
  const int wq = t >> 6;            // 0..7
  const int lr = lane & 15, lg = lane >> 4;

  int koff0, koff1, voff0, voff1;
  { int c = t;       int kr = c >> 4, kc = c & 15; koff0 = kr*DD + ((kc ^ (kr & 7)) * 8); }
  { int c = 512 + t; int kr = c >> 4, kc = c & 15; koff1 = kr*DD + ((kc ^ (kr & 7)) * 8); }
  { int c = t;       int vd = c >> 3, vc = c & 7;  voff0 = vd*SS + ((vc ^ (vd & 7)) * 8); }
  { int c = 512 + t; int vd = c >> 3, vc = c & 7;  voff1 = vd*SS + ((vc ^ (vd & 7)) * 8); }
  const ushort* Kg = Kb + (long)(b * SS) * DD + h * HDIM;
  const ushort* Vg = Vtg + (long)(bh * HDIM) * SS;

#define STAGE(KT, BUF) do {                                   \
    const ushort* kg_ = Kg + (long)(KT) * 64 * DD;            \
    const ushort* vg_ = Vg + (KT) * 64;                       \
    gld_lds16(kg_ + koff0, &Ks[BUF][t*8]);                    \
    gld_lds16(kg_ + koff1, &Ks[BUF][4096 + t*8]);             \
    gld_lds16(vg_ + voff0, &Vs[BUF][t*8]);                    \
    gld_lds16(vg_ + voff1, &Vs[BUF][4096 + t*8]); } while (0)

  ushort* myP = Ps + wq * (16*68);
  int cur = 0;

  STAGE(0, 0);
  __syncthreads();

  for (int half = 0; half < 2; ++half) {
    const int qt = half ? (15 - p) : p;
    const int qbase = qt * 128;
    const long rowQ = (long)(b * SS + qbase + wq * 16);
    const int ntile = 2*qt + 2;
    const int qminw = qbase + wq*16;
    const int qmaxw = qminw + 15;

    bf16x8 qf[4];
#pragma unroll
    for (int c = 0; c < 4; ++c)
      qf[c] = *(const bf16x8*)(Qb + (rowQ + lr) * DD + h*HDIM + c*32 + lg*8);

    f32x4 accO[8] = {};
    float mrow[4], lrow[4];
#pragma unroll
    for (int j = 0; j < 4; ++j) { mrow[j] = -1e30f; lrow[j] = 0.f; }

    for (int kt = 0; kt < ntile; ++kt) {
      const int k0 = kt * 64;
      const bool last = (half == 1) && (kt == ntile - 1);
      if (!last) {
        const int ktn = (kt + 1 < ntile) ? (kt + 1) : 0;
        STAGE(ktn, cur ^ 1);
      }

      if (k0 <= qmaxw) {
        const ushort* Kc = Ks[cur];
        const ushort* Vc = Vs[cur];
        f32x4 sc[4] = {};
        __builtin_amdgcn_s_setprio(1);
#pragma unroll
        for (int n = 0; n < 4; ++n) {
          int r = n*16 + lr;
          int swz = (r & 7) << 4;
#pragma unroll
          for (int c = 0; c < 4; ++c) {
            bf16x8 kf = *(const bf16x8*)((const char*)Kc + ((r*256 + c*64 + lg*16) ^ swz));
            sc[n] = __builtin_amdgcn_mfma_f32_16x16x32_bf16(qf[c], kf, sc[n], 0,0,0);
          }
        }
        __builtin_amdgcn_s_setprio(0);
        if (k0 + 63 > qminw) {
#pragma unroll
          for (int n = 0; n < 4; ++n)
#pragma unroll
            for (int j = 0; j < 4; ++j) {
              int kpos = k0 + n*16 + lr;
              int qpos = qminw + lg*4 + j;
              if (kpos > qpos) sc[n][j] = -1e30f;
            }
        }
        float al[4];
#pragma unroll
        for (int j = 0; j < 4; ++j) {
          float tm = fmaxf(fmaxf(sc[0][j], sc[1][j]), fmaxf(sc[2][j], sc[3][j]));
#pragma unroll
          for (int off = 1; off < 16; off <<= 1) tm = fmaxf(tm, __shfl_xor(tm, off));
          float mn = fmaxf(mrow[j], tm);
          float a = fast_exp2(mrow[j] - mn);
          mrow[j] = mn;
          float ts = 0.f;
#pragma unroll
          for (int n = 0; n < 4; ++n) {
            float pv = fast_exp2(sc[n][j] - mn);
            sc[n][j] = pv; ts += pv;
          }
#pragma unroll
          for (int off = 1; off < 16; off <<= 1) ts += __shfl_xor(ts, off);
          lrow[j] = lrow[j] * a + ts;
          al[j] = a;
        }
#pragma unroll
        for (int dg = 0; dg < 8; ++dg) {
          f32x4 v = accO[dg];
          v[0] *= al[0]; v[1] *= al[1]; v[2] *= al[2]; v[3] *= al[3];
          accO[dg] = v;
        }
#pragma unroll
        for (int n = 0; n < 4; ++n)
#pragma unroll
          for (int j = 0; j < 4; ++j)
            myP[(lg*4 + j)*68 + n*16 + lr] = f2bf(sc[n][j]);
        bf16x8 pa0 = *(const bf16x8*)(myP + lr*68 + lg*8);
        bf16x8 pa1 = *(const bf16x8*)(myP + lr*68 + 32 + lg*8);
        __builtin_amdgcn_s_setprio(1);
#pragma unroll
        for (int dg = 0; dg < 8; ++dg) {
          int d = dg*16 + lr;
          int vswz = (d & 7) << 4;
          bf16x8 v0 = *(const bf16x8*)((const char*)Vc + ((d*128 + lg*16) ^ vswz));
          bf16x8 v1 = *(const bf16x8*)((const char*)Vc + ((d*128 + 64 + lg*16) ^ vswz));
          accO[dg] = __builtin_amdgcn_mfma_f32_16x16x32_bf16(pa0, v0, accO[dg], 0,0,0);
          accO[dg] = __builtin_amdgcn_mfma_f32_16x16x32_bf16(pa1, v1, accO[dg], 0,0,0);
        }
        __builtin_amdgcn_s_setprio(0);
      }
      __syncthreads();
      cur ^= 1;
    }

    float inv[4];
#pragma unroll
    for (int j = 0; j < 4; ++j) inv[j] = 1.0f / lrow[j];
    ushort* Og = Ob + rowQ * DD + h * HDIM;
#pragma unroll
    for (int dg = 0; dg < 8; ++dg)
#pragma unroll
      for (int j = 0; j < 4; ++j)
        Og[(long)(lg*4 + j) * DD + dg*16 + lr] = f2bf(accO[dg][j] * inv[j]);
  }
#undef STAGE
}

// ---------------- launch ----------------------------------------------------
extern "C" void kernel_launch(void* const* d_in, const int* in_sizes, int n_in,
                              void* d_out, int out_size, void* d_ws, size_t ws_size,
                              hipStream_t stream) {
  const float* x  = (const float*)d_in[0];
  const float* Wq = (const float*)d_in[1];
  const float* Wk = (const float*)d_in[2];
  const float* Wv = (const float*)d_in[3];
  const float* Wo = (const float*)d_in[4];

  ushort* ws  = (ushort*)d_ws;
  ushort* xb  = ws;                         // x bf16; later reused as attn-out
  ushort* wqb = ws  + (long)MM*DD;          // wq/wk/wv contiguous = fused Bt
  ushort* wkb = wqb + (long)DD*DD;
  ushort* wvb = wkb + (long)DD*DD;
  ushort* wob = wvb + (long)DD*DD;
  ushort* Qb  = wob + (long)DD*DD;
  ushort* Kb  = Qb  + (long)MM*DD;
  ushort* Vtg = Kb  + (long)MM*DD;          // V stored transposed [bh*128+d][s]
  (void)wkb; (void)wvb;

  const int CVT_BLOCKS = (MM*DD + 4*DD*DD) / 8 / 256;   // 12288
  cvt_all<<<CVT_BLOCKS, 256, 0, stream>>>(x, Wq, Wk, Wv, Wo, ws);

  gemm8p<<<384, 512, 0, stream>>>(xb, wqb, Qb, Kb, Vtg);

  attn_fwd<<<256, 512, 0, stream>>>(Qb, Kb, Vtg, xb);   // attn out -> xb

  gemm_tri<1><<<256, 256, 0, stream>>>(xb, wob, (float*)d_out);
}

// Round 14
// 263.066 us; speedup vs baseline: 1.0332x; 1.0332x over previous
//
#include <hip/hip_runtime.h>
#include <stdint.h>

#define DD 2048
#define SS 2048
#define NB 2
#define NH 16
#define HDIM 128
#define MM (NB*SS)   // 4096 rows

typedef __attribute__((ext_vector_type(8))) short bf16x8;
typedef __attribute__((ext_vector_type(4))) float f32x4;
typedef __attribute__((ext_vector_type(4))) ushort u16x4;

__device__ __forceinline__ float fast_exp2(float x) {
  return __builtin_amdgcn_exp2f(x);   // v_exp_f32 (2^x natively)
}

__device__ __forceinline__ ushort f2bf(float f) {
  union { float f; uint32_t u; } v; v.f = f;
  uint32_t u = v.u;
  return (ushort)((u + 0x7fffu + ((u >> 16) & 1u)) >> 16);
}

__device__ __forceinline__ void gld_lds16(const ushort* g, ushort* l) {
  __builtin_amdgcn_global_load_lds(
      (const __attribute__((address_space(1))) void*)g,
      (__attribute__((address_space(3))) void*)l, 16, 0, 0);
}

// ---------------- fp32 -> bf16 conversion of x and the 4 weights -------------
__global__ __launch_bounds__(256) void cvt_all(
    const float* __restrict__ x, const float* __restrict__ wq,
    const float* __restrict__ wk, const float* __restrict__ wv,
    const float* __restrict__ wo, ushort* __restrict__ dst)
{
  int i8 = blockIdx.x * 256 + threadIdx.x;   // one 8-float chunk per thread
  const int X8 = MM * DD / 8;                // 1,048,576
  const int W8 = DD * DD / 8;                // 524,288
  const float* src; int off;
  if (i8 < X8)            { src = x;  off = i8; }
  else if (i8 < X8 +   W8){ src = wq; off = i8 - X8; }
  else if (i8 < X8 + 2*W8){ src = wk; off = i8 - (X8 +   W8); }
  else if (i8 < X8 + 3*W8){ src = wv; off = i8 - (X8 + 2*W8); }
  else                    { src = wo; off = i8 - (X8 + 3*W8); }
  const float4* p = (const float4*)src;
  float4 a = p[(long)off*2], b = p[(long)off*2 + 1];
  bf16x8 o;
  o[0]=(short)f2bf(a.x); o[1]=(short)f2bf(a.y); o[2]=(short)f2bf(a.z); o[3]=(short)f2bf(a.w);
  o[4]=(short)f2bf(b.x); o[5]=(short)f2bf(b.y); o[6]=(short)f2bf(b.z); o[7]=(short)f2bf(b.w);
  *(bf16x8*)(dst + (long)i8*8) = o;
}

// ---- GEMM: 256x128 tile, BK=32, 4 waves (each 128x64), TRIPLE buffer -------
// (R12-verified: QKV 115 us / 39% MfmaUtil; best of 7 schedule variants)
template<int MODE>
__global__ __launch_bounds__(256, 2) void gemm_tri(
    const ushort* __restrict__ A, const ushort* __restrict__ Bt,
    ushort* __restrict__ Qo, ushort* __restrict__ Ko, ushort* __restrict__ Vt,
    float* __restrict__ Cf)
{
  __shared__ ushort lds[3 * 12288];          // 3 x 24 KB = 72 KB
  const int t = threadIdx.x;
  const int bid = blockIdx.x;
  const int xcd = bid & 7, local = bid >> 3;
  const int NBX = (MODE == 0) ? 6 : 2;       // n-tiles per XCD chunk
  const int bm = local / NBX;
  const int bn = xcd * NBX + (local - bm * NBX);
  const int lane = t & 63, w = t >> 6;       // 4 waves
  const int wr = w >> 1, wcn = w & 1;        // 2M x 2N; per-wave 128x64
  const int lr = lane & 15, lg = lane >> 4;  // lg 0..3

  int aoff[4], boff[2];
#pragma unroll
  for (int i = 0; i < 4; ++i) {
    int p = i*256 + t, ln = p >> 3, sr = (p & 7) ^ (ln & 7);
    aoff[i] = (2*ln + (sr >> 2)) * DD + (sr & 3) * 8;
  }
#pragma unroll
  for (int i = 0; i < 2; ++i) {
    int p = i*256 + t, ln = p >> 3, sr = (p & 7) ^ (ln & 7);
    boff[i] = (2*ln + (sr >> 2)) * DD + (sr & 3) * 8;
  }
  const ushort* Ab = A  + (long)(bm*256) * DD;
  const ushort* Bb = Bt + (long)(bn*128) * DD;

#define STG_A01(KT, BUF) do { const ushort* g_ = Ab + (KT)*32;             \
    ushort* l_ = lds + (BUF)*12288;                                        \
    gld_lds16(g_ + aoff[0], l_ + t*8);                                     \
    gld_lds16(g_ + aoff[1], l_ + (256 + t)*8); } while (0)
#define STG_A23(KT, BUF) do { const ushort* g_ = Ab + (KT)*32;             \
    ushort* l_ = lds + (BUF)*12288;                                        \
    gld_lds16(g_ + aoff[2], l_ + (512 + t)*8);                             \
    gld_lds16(g_ + aoff[3], l_ + (768 + t)*8); } while (0)
#define STG_B(KT, BUF)   do { const ushort* g_ = Bb + (KT)*32;             \
    ushort* l_ = lds + (BUF)*12288 + 8192;                                 \
    gld_lds16(g_ + boff[0], l_ + t*8);                                     \
    gld_lds16(g_ + boff[1], l_ + (256 + t)*8); } while (0)
#define LDA(dst, m) { int r_ = wr*128 + (m)*16 + lr; int ln_ = r_ >> 1;    \
    int sl_ = (lg + ((r_ & 1) << 2)) ^ (ln_ & 7);                          \
    (dst) = *(const bf16x8*)(cb + ln_*128 + sl_*16); }
#define LDB(dst, n) { int r_ = wcn*64 + (n)*16 + lr; int ln_ = r_ >> 1;    \
    int sl_ = (lg + ((r_ & 1) << 2)) ^ (ln_ & 7);                          \
    (dst) = *(const bf16x8*)(cb + 16384 + ln_*128 + sl_*16); }
#define MFMA42(AV, BV, MB, NB_) do {                                       \
    __builtin_amdgcn_s_setprio(1);                                         \
    _Pragma("unroll") for (int m = 0; m < 4; ++m)                          \
    _Pragma("unroll") for (int n = 0; n < 2; ++n)                          \
      acc[(MB)+m][(NB_)+n] = __builtin_amdgcn_mfma_f32_16x16x32_bf16(      \
          AV[m], BV[n], acc[(MB)+m][(NB_)+n], 0, 0, 0);                    \
    __builtin_amdgcn_s_setprio(0); } while (0)
#define SB  __builtin_amdgcn_sched_barrier(0)
#define BAR __builtin_amdgcn_s_barrier()
#define LGKM0 asm volatile("s_waitcnt lgkmcnt(0)" ::: "memory")

  f32x4 acc[8][4] = {};
  const int T = DD / 32;                     // 64 K-tiles

  STG_A01(0, 0); STG_A23(0, 0); STG_B(0, 0);
  STG_A01(1, 1); STG_A23(1, 1); STG_B(1, 1);
  asm volatile("s_waitcnt vmcnt(6)" ::: "memory");
  SB; BAR; SB;

  for (int kt = 0; kt < T; ++kt) {
    const char* cb = (const char*)lds + (kt % 3) * 24576;
    const int bs = (kt + 2) % 3;
    const bool st = (kt + 2 < T);
    bf16x8 a03[4], a47[4], b01[2], b23[2];
    LDA(a03[0],0); LDA(a03[1],1); LDA(a03[2],2); LDA(a03[3],3);
    LDB(b01[0],0); LDB(b01[1],1);
    if (st) STG_A01(kt+2, bs);
    SB; BAR; LGKM0; SB;
    MFMA42(a03, b01, 0, 0);
    SB; BAR; SB;
    LDA(a47[0],4); LDA(a47[1],5); LDA(a47[2],6); LDA(a47[3],7);
    if (st) STG_A23(kt+2, bs);
    SB; BAR; LGKM0; SB;
    MFMA42(a47, b01, 4, 0);
    SB; BAR; SB;
    LDB(b23[0],2); LDB(b23[1],3);
    if (st) STG_B(kt+2, bs);
    SB; BAR; LGKM0; SB;
    MFMA42(a03, b23, 0, 2);
    SB; BAR; SB;
    if (st)              { asm volatile("s_waitcnt vmcnt(6)" ::: "memory"); }
    else if (kt + 1 < T) { asm volatile("s_waitcnt vmcnt(0)" ::: "memory"); }
    SB; BAR; SB;
    MFMA42(a47, b23, 4, 2);
    SB; BAR; SB;
  }
#undef STG_A01
#undef STG_A23
#undef STG_B
#undef LDA
#undef LDB
#undef MFMA42
#undef SB
#undef BAR
#undef LGKM0

  const int crb = bm*256 + wr*128 + lg*4;
  if (MODE == 0) {
    const int region = bn >> 4;              // 0=Q, 1=K, 2=V (16 bn each)
    const int ccb = (bn & 15)*128 + wcn*64 + lr;
    if (region < 2) {
      const float scale = (region == 0) ? (0.08838834764831845f * 1.4426950408889634f) : 1.0f;
      ushort* C = (region == 0) ? Qo : Ko;
#pragma unroll
      for (int m = 0; m < 8; ++m)
#pragma unroll
        for (int n = 0; n < 4; ++n)
#pragma unroll
          for (int j = 0; j < 4; ++j)
            C[(long)(crb + m*16 + j) * DD + (ccb + n*16)] = f2bf(acc[m][n][j] * scale);
    } else {
#pragma unroll
      for (int m = 0; m < 8; ++m) {
        int sg = crb + m*16;
        int b2 = sg >> 11, s2 = sg & 2047;
#pragma unroll
        for (int n = 0; n < 4; ++n) {
          int colv = ccb + n*16;
          int h2 = colv >> 7, d2 = colv & 127;
          u16x4 pk;
          pk[0] = f2bf(acc[m][n][0]); pk[1] = f2bf(acc[m][n][1]);
          pk[2] = f2bf(acc[m][n][2]); pk[3] = f2bf(acc[m][n][3]);
          *(u16x4*)(Vt + ((long)((b2*NH + h2)*HDIM + d2)) * SS + s2) = pk;
        }
      }
    }
  } else {
    const int ccb = bn*128 + wcn*64 + lr;
#pragma unroll
    for (int m = 0; m < 8; ++m)
#pragma unroll
      for (int n = 0; n < 4; ++n)
#pragma unroll
        for (int j = 0; j < 4; ++j)
          Cf[(long)(crb + m*16 + j) * DD + (ccb + n*16)] = acc[m][n][j];
  }
}

// ------ causal flash attention: TRIPLE-buffered pipeline + pair-balance ------
// 8 waves x 16 q-rows. vs R12: K/V triple buffer, 2-tile lookahead, counted
// s_waitcnt vmcnt(4) (tile u+1's 4 loads stay in flight across the barrier;
// in-order vmcnt => tile u landed). STAGE placed AFTER the barrier so the
// overwritten buffer (held tile u-1) is provably free. vmcnt(0) only at the
// final tile. Linear tile counter u runs across both paired q-tiles (34).
__global__ __launch_bounds__(512, 2) void attn_fwd(
    const ushort* __restrict__ Qb, const ushort* __restrict__ Kb,
    const ushort* __restrict__ Vtg, ushort* __restrict__ Ob)
{
  __shared__ ushort Ks[3][64*128];  // 3 x 16 KB, [k][d] XOR-swizzled chunks
  __shared__ ushort Vs[3][128*64];  // 3 x 16 KB, [d][k] XOR-swizzled chunks
  __shared__ ushort Ps[8*16*68];    // per-wave P [16][64], pad 68 (2-way)

  const int bid = blockIdx.x;       // 256 blocks: p(8) x bh(32)
  const int p = bid >> 5;           // 0..7
  const int bh = bid & 31;
  const int b = bh >> 4, h = bh & 15;
  const int t = threadIdx.x;
  const int lane = t & 63;
  const int wq = t >> 6;            // 0..7
  const int lr = lane & 15, lg = lane >> 4;

  int koff0, koff1, voff0, voff1;
  { int c = t;       int kr = c >> 4, kc = c & 15; koff0 = kr*DD + ((kc ^ (kr & 7)) * 8); }
  { int c = 512 + t; int kr = c >> 4, kc = c & 15; koff1 = kr*DD + ((kc ^ (kr & 7)) * 8); }
  { int c = t;       int vd = c >> 3, vc = c & 7;  voff0 = vd*SS + ((vc ^ (vd & 7)) * 8); }
  { int c = 512 + t; int vd = c >> 3, vc = c & 7;  voff1 = vd*SS + ((vc ^ (vd & 7)) * 8); }
  const ushort* Kg = Kb + (long)(b * SS) * DD + h * HDIM;
  const ushort* Vg = Vtg + (long)(bh * HDIM) * SS;

#define STAGE(KT, BUF) do {                                   \
    const ushort* kg_ = Kg + (long)(KT) * 64 * DD;            \
    const ushort* vg_ = Vg + (KT) * 64;                       \
    gld_lds16(kg_ + koff0, &Ks[BUF][t*8]);                    \
    gld_lds16(kg_ + koff1, &Ks[BUF][4096 + t*8]);             \
    gld_lds16(vg_ + voff0, &Vs[BUF][t*8]);                    \
    gld_lds16(vg_ + voff1, &Vs[BUF][4096 + t*8]); } while (0)

  ushort* myP = Ps + wq * (16*68);
  const int n0 = 2*p + 2;           // half-0 tile count
  const int TOT = 34;               // n0 + (2(15-p)+2)

  // prologue: tiles 0,1 of half 0 -> bufs 0,1 (2-deep pipeline)
  STAGE(0, 0);
  STAGE(1, 1);

  int u = 0;                        // linear tile counter across halves
  for (int half = 0; half < 2; ++half) {
    const int qt = half ? (15 - p) : p;
    const int qbase = qt * 128;
    const long rowQ = (long)(b * SS + qbase + wq * 16);
    const int ntile = 2*qt + 2;
    const int qminw = qbase + wq*16;
    const int qmaxw = qminw + 15;

    bf16x8 qf[4];
#pragma unroll
    for (int c = 0; c < 4; ++c)
      qf[c] = *(const bf16x8*)(Qb + (rowQ + lr) * DD + h*HDIM + c*32 + lg*8);

    f32x4 accO[8] = {};
    float mrow[4], lrow[4];
#pragma unroll
    for (int j = 0; j < 4; ++j) { mrow[j] = -1e30f; lrow[j] = 0.f; }

    for (int kt = 0; kt < ntile; ++kt, ++u) {
      const int k0 = kt * 64;
      // counted wait: tile u+1's 4 loads (newest) may stay in flight
      if (u + 1 < TOT) { asm volatile("s_waitcnt vmcnt(4)" ::: "memory"); }
      else             { asm volatile("s_waitcnt vmcnt(0)" ::: "memory"); }
      __builtin_amdgcn_sched_barrier(0);
      __syncthreads();               // all waves done with tile u-1's buffer
      __builtin_amdgcn_sched_barrier(0);
      if (u + 2 < TOT) {             // stage tile u+2 into freed buffer
        const int un = u + 2;
        const int ktn = (un < n0) ? un : un - n0;
        STAGE(ktn, un % 3);
      }

      if (k0 <= qmaxw) {
        const ushort* Kc = Ks[u % 3];
        const ushort* Vc = Vs[u % 3];
        f32x4 sc[4] = {};
        __builtin_amdgcn_s_setprio(1);
#pragma unroll
        for (int n = 0; n < 4; ++n) {
          int r = n*16 + lr;
          int swz = (r & 7) << 4;
#pragma unroll
          for (int c = 0; c < 4; ++c) {
            bf16x8 kf = *(const bf16x8*)((const char*)Kc + ((r*256 + c*64 + lg*16) ^ swz));
            sc[n] = __builtin_amdgcn_mfma_f32_16x16x32_bf16(qf[c], kf, sc[n], 0,0,0);
          }
        }
        __builtin_amdgcn_s_setprio(0);
        if (k0 + 63 > qminw) {       // diagonal tiles: causal mask
#pragma unroll
          for (int n = 0; n < 4; ++n)
#pragma unroll
            for (int j = 0; j < 4; ++j) {
              int kpos = k0 + n*16 + lr;
              int qpos = qminw + lg*4 + j;
              if (kpos > qpos) sc[n][j] = -1e30f;
            }
        }
        float al[4];
#pragma unroll
        for (int j = 0; j < 4; ++j) {  // online softmax (log2 domain)
          float tm = fmaxf(fmaxf(sc[0][j], sc[1][j]), fmaxf(sc[2][j], sc[3][j]));
#pragma unroll
          for (int off = 1; off < 16; off <<= 1) tm = fmaxf(tm, __shfl_xor(tm, off));
          float mn = fmaxf(mrow[j], tm);
          float a = fast_exp2(mrow[j] - mn);
          mrow[j] = mn;
          float ts = 0.f;
#pragma unroll
          for (int n = 0; n < 4; ++n) {
            float pv = fast_exp2(sc[n][j] - mn);
            sc[n][j] = pv; ts += pv;
          }
#pragma unroll
          for (int off = 1; off < 16; off <<= 1) ts += __shfl_xor(ts, off);
          lrow[j] = lrow[j] * a + ts;
          al[j] = a;
        }
#pragma unroll
        for (int dg = 0; dg < 8; ++dg) {
          f32x4 v = accO[dg];
          v[0] *= al[0]; v[1] *= al[1]; v[2] *= al[2]; v[3] *= al[3];
          accO[dg] = v;
        }
#pragma unroll
        for (int n = 0; n < 4; ++n)  // P -> per-wave LDS (D-layout -> A-layout)
#pragma unroll
          for (int j = 0; j < 4; ++j)
            myP[(lg*4 + j)*68 + n*16 + lr] = f2bf(sc[n][j]);
        bf16x8 pa0 = *(const bf16x8*)(myP + lr*68 + lg*8);
        bf16x8 pa1 = *(const bf16x8*)(myP + lr*68 + 32 + lg*8);
        __builtin_amdgcn_s_setprio(1);
#pragma unroll
        for (int dg = 0; dg < 8; ++dg) {  // O += P V
          int d = dg*16 + lr;
          int vswz = (d & 7) << 4;
          bf16x8 v0 = *(const bf16x8*)((const char*)Vc + ((d*128 + lg*16) ^ vswz));
          bf16x8 v1 = *(const bf16x8*)((const char*)Vc + ((d*128 + 64 + lg*16) ^ vswz));
          accO[dg] = __builtin_amdgcn_mfma_f32_16x16x32_bf16(pa0, v0, accO[dg], 0,0,0);
          accO[dg] = __builtin_amdgcn_mfma_f32_16x16x32_bf16(pa1, v1, accO[dg], 0,0,0);
        }
        __builtin_amdgcn_s_setprio(0);
      }
    }

    float inv[4];
#pragma unroll
    for (int j = 0; j < 4; ++j) inv[j] = 1.0f / lrow[j];
    ushort* Og = Ob + rowQ * DD + h * HDIM;
#pragma unroll
    for (int dg = 0; dg < 8; ++dg)
#pragma unroll
      for (int j = 0; j < 4; ++j)
        Og[(long)(lg*4 + j) * DD + dg*16 + lr] = f2bf(accO[dg][j] * inv[j]);
  }
#undef STAGE
}

// ---------------- launch ----------------------------------------------------
extern "C" void kernel_launch(void* const* d_in, const int* in_sizes, int n_in,
                              void* d_out, int out_size, void* d_ws, size_t ws_size,
                              hipStream_t stream) {
  const float* x  = (const float*)d_in[0];
  const float* Wq = (const float*)d_in[1];
  const float* Wk = (const float*)d_in[2];
  const float* Wv = (const float*)d_in[3];
  const float* Wo = (const float*)d_in[4];

  ushort* ws  = (ushort*)d_ws;
  ushort* xb  = ws;                         // x bf16; later reused as attn-out
  ushort* wqb = ws  + (long)MM*DD;          // wq/wk/wv contiguous = fused Bt
  ushort* wkb = wqb + (long)DD*DD;
  ushort* wvb = wkb + (long)DD*DD;
  ushort* wob = wvb + (long)DD*DD;
  ushort* Qb  = wob + (long)DD*DD;
  ushort* Kb  = Qb  + (long)MM*DD;
  ushort* Vtg = Kb  + (long)MM*DD;          // V stored transposed [bh*128+d][s]
  (void)wkb; (void)wvb;

  const int CVT_BLOCKS = (MM*DD + 4*DD*DD) / 8 / 256;   // 12288
  cvt_all<<<CVT_BLOCKS, 256, 0, stream>>>(x, Wq, Wk, Wv, Wo, ws);

  gemm_tri<0><<<768, 256, 0, stream>>>(xb, wqb, Qb, Kb, Vtg, nullptr);

  attn_fwd<<<256, 512, 0, stream>>>(Qb, Kb, Vtg, xb);   // attn out -> xb

  gemm_tri<1><<<256, 256, 0, stream>>>(xb, wob, nullptr, nullptr, nullptr,
                                       (float*)d_out);
}

// Round 15
// 250.526 us; speedup vs baseline: 1.0849x; 1.0501x over previous
//
#include <hip/hip_runtime.h>
#include <stdint.h>

#define DD 2048
#define SS 2048
#define NB 2
#define NH 16
#define HDIM 128
#define MM (NB*SS)   // 4096 rows

typedef __attribute__((ext_vector_type(8))) short bf16x8;
typedef __attribute__((ext_vector_type(4))) float f32x4;
typedef __attribute__((ext_vector_type(4))) ushort u16x4;

__device__ __forceinline__ float fast_exp2(float x) {
  return __builtin_amdgcn_exp2f(x);   // v_exp_f32 (2^x natively)
}

__device__ __forceinline__ ushort f2bf(float f) {
  union { float f; uint32_t u; } v; v.f = f;
  uint32_t u = v.u;
  return (ushort)((u + 0x7fffu + ((u >> 16) & 1u)) >> 16);
}

__device__ __forceinline__ void gld_lds16(const ushort* g, ushort* l) {
  __builtin_amdgcn_global_load_lds(
      (const __attribute__((address_space(1))) void*)g,
      (__attribute__((address_space(3))) void*)l, 16, 0, 0);
}

// ---------------- fp32 -> bf16 conversion of x and the 4 weights -------------
__global__ __launch_bounds__(256) void cvt_all(
    const float* __restrict__ x, const float* __restrict__ wq,
    const float* __restrict__ wk, const float* __restrict__ wv,
    const float* __restrict__ wo, ushort* __restrict__ dst)
{
  int i8 = blockIdx.x * 256 + threadIdx.x;   // one 8-float chunk per thread
  const int X8 = MM * DD / 8;                // 1,048,576
  const int W8 = DD * DD / 8;                // 524,288
  const float* src; int off;
  if (i8 < X8)            { src = x;  off = i8; }
  else if (i8 < X8 +   W8){ src = wq; off = i8 - X8; }
  else if (i8 < X8 + 2*W8){ src = wk; off = i8 - (X8 +   W8); }
  else if (i8 < X8 + 3*W8){ src = wv; off = i8 - (X8 + 2*W8); }
  else                    { src = wo; off = i8 - (X8 + 3*W8); }
  const float4* p = (const float4*)src;
  float4 a = p[(long)off*2], b = p[(long)off*2 + 1];
  bf16x8 o;
  o[0]=(short)f2bf(a.x); o[1]=(short)f2bf(a.y); o[2]=(short)f2bf(a.z); o[3]=(short)f2bf(a.w);
  o[4]=(short)f2bf(b.x); o[5]=(short)f2bf(b.y); o[6]=(short)f2bf(b.z); o[7]=(short)f2bf(b.w);
  *(bf16x8*)(dst + (long)i8*8) = o;
}

// ---- GEMM: 256x128 tile, BK=32, 4 waves (each 128x64), TRIPLE buffer -------
// (R12-verified: QKV 115 us / 39% MfmaUtil; best of 7 schedule variants)
template<int MODE>
__global__ __launch_bounds__(256, 2) void gemm_tri(
    const ushort* __restrict__ A, const ushort* __restrict__ Bt,
    ushort* __restrict__ Qo, ushort* __restrict__ Ko, ushort* __restrict__ Vt,
    float* __restrict__ Cf)
{
  __shared__ ushort lds[3 * 12288];          // 3 x 24 KB = 72 KB
  const int t = threadIdx.x;
  const int bid = blockIdx.x;
  const int xcd = bid & 7, local = bid >> 3;
  const int NBX = (MODE == 0) ? 6 : 2;       // n-tiles per XCD chunk
  const int bm = local / NBX;
  const int bn = xcd * NBX + (local - bm * NBX);
  const int lane = t & 63, w = t >> 6;       // 4 waves
  const int wr = w >> 1, wcn = w & 1;        // 2M x 2N; per-wave 128x64
  const int lr = lane & 15, lg = lane >> 4;  // lg 0..3

  int aoff[4], boff[2];
#pragma unroll
  for (int i = 0; i < 4; ++i) {
    int p = i*256 + t, ln = p >> 3, sr = (p & 7) ^ (ln & 7);
    aoff[i] = (2*ln + (sr >> 2)) * DD + (sr & 3) * 8;
  }
#pragma unroll
  for (int i = 0; i < 2; ++i) {
    int p = i*256 + t, ln = p >> 3, sr = (p & 7) ^ (ln & 7);
    boff[i] = (2*ln + (sr >> 2)) * DD + (sr & 3) * 8;
  }
  const ushort* Ab = A  + (long)(bm*256) * DD;
  const ushort* Bb = Bt + (long)(bn*128) * DD;

#define STG_A01(KT, BUF) do { const ushort* g_ = Ab + (KT)*32;             \
    ushort* l_ = lds + (BUF)*12288;                                        \
    gld_lds16(g_ + aoff[0], l_ + t*8);                                     \
    gld_lds16(g_ + aoff[1], l_ + (256 + t)*8); } while (0)
#define STG_A23(KT, BUF) do { const ushort* g_ = Ab + (KT)*32;             \
    ushort* l_ = lds + (BUF)*12288;                                        \
    gld_lds16(g_ + aoff[2], l_ + (512 + t)*8);                             \
    gld_lds16(g_ + aoff[3], l_ + (768 + t)*8); } while (0)
#define STG_B(KT, BUF)   do { const ushort* g_ = Bb + (KT)*32;             \
    ushort* l_ = lds + (BUF)*12288 + 8192;                                 \
    gld_lds16(g_ + boff[0], l_ + t*8);                                     \
    gld_lds16(g_ + boff[1], l_ + (256 + t)*8); } while (0)
#define LDA(dst, m) { int r_ = wr*128 + (m)*16 + lr; int ln_ = r_ >> 1;    \
    int sl_ = (lg + ((r_ & 1) << 2)) ^ (ln_ & 7);                          \
    (dst) = *(const bf16x8*)(cb + ln_*128 + sl_*16); }
#define LDB(dst, n) { int r_ = wcn*64 + (n)*16 + lr; int ln_ = r_ >> 1;    \
    int sl_ = (lg + ((r_ & 1) << 2)) ^ (ln_ & 7);                          \
    (dst) = *(const bf16x8*)(cb + 16384 + ln_*128 + sl_*16); }
#define MFMA42(AV, BV, MB, NB_) do {                                       \
    __builtin_amdgcn_s_setprio(1);                                         \
    _Pragma("unroll") for (int m = 0; m < 4; ++m)                          \
    _Pragma("unroll") for (int n = 0; n < 2; ++n)                          \
      acc[(MB)+m][(NB_)+n] = __builtin_amdgcn_mfma_f32_16x16x32_bf16(      \
          AV[m], BV[n], acc[(MB)+m][(NB_)+n], 0, 0, 0);                    \
    __builtin_amdgcn_s_setprio(0); } while (0)
#define SB  __builtin_amdgcn_sched_barrier(0)
#define BAR __builtin_amdgcn_s_barrier()
#define LGKM0 asm volatile("s_waitcnt lgkmcnt(0)" ::: "memory")

  f32x4 acc[8][4] = {};
  const int T = DD / 32;                     // 64 K-tiles

  STG_A01(0, 0); STG_A23(0, 0); STG_B(0, 0);
  STG_A01(1, 1); STG_A23(1, 1); STG_B(1, 1);
  asm volatile("s_waitcnt vmcnt(6)" ::: "memory");
  SB; BAR; SB;

  for (int kt = 0; kt < T; ++kt) {
    const char* cb = (const char*)lds + (kt % 3) * 24576;
    const int bs = (kt + 2) % 3;
    const bool st = (kt + 2 < T);
    bf16x8 a03[4], a47[4], b01[2], b23[2];
    LDA(a03[0],0); LDA(a03[1],1); LDA(a03[2],2); LDA(a03[3],3);
    LDB(b01[0],0); LDB(b01[1],1);
    if (st) STG_A01(kt+2, bs);
    SB; BAR; LGKM0; SB;
    MFMA42(a03, b01, 0, 0);
    SB; BAR; SB;
    LDA(a47[0],4); LDA(a47[1],5); LDA(a47[2],6); LDA(a47[3],7);
    if (st) STG_A23(kt+2, bs);
    SB; BAR; LGKM0; SB;
    MFMA42(a47, b01, 4, 0);
    SB; BAR; SB;
    LDB(b23[0],2); LDB(b23[1],3);
    if (st) STG_B(kt+2, bs);
    SB; BAR; LGKM0; SB;
    MFMA42(a03, b23, 0, 2);
    SB; BAR; SB;
    if (st)              { asm volatile("s_waitcnt vmcnt(6)" ::: "memory"); }
    else if (kt + 1 < T) { asm volatile("s_waitcnt vmcnt(0)" ::: "memory"); }
    SB; BAR; SB;
    MFMA42(a47, b23, 4, 2);
    SB; BAR; SB;
  }
#undef STG_A01
#undef STG_A23
#undef STG_B
#undef LDA
#undef LDB
#undef MFMA42
#undef SB
#undef BAR
#undef LGKM0

  const int crb = bm*256 + wr*128 + lg*4;
  if (MODE == 0) {
    const int region = bn >> 4;              // 0=Q, 1=K, 2=V (16 bn each)
    const int ccb = (bn & 15)*128 + wcn*64 + lr;
    if (region < 2) {
      const float scale = (region == 0) ? (0.08838834764831845f * 1.4426950408889634f) : 1.0f;
      ushort* C = (region == 0) ? Qo : Ko;
#pragma unroll
      for (int m = 0; m < 8; ++m)
#pragma unroll
        for (int n = 0; n < 4; ++n)
#pragma unroll
          for (int j = 0; j < 4; ++j)
            C[(long)(crb + m*16 + j) * DD + (ccb + n*16)] = f2bf(acc[m][n][j] * scale);
    } else {
#pragma unroll
      for (int m = 0; m < 8; ++m) {
        int sg = crb + m*16;
        int b2 = sg >> 11, s2 = sg & 2047;
#pragma unroll
        for (int n = 0; n < 4; ++n) {
          int colv = ccb + n*16;
          int h2 = colv >> 7, d2 = colv & 127;
          u16x4 pk;
          pk[0] = f2bf(acc[m][n][0]); pk[1] = f2bf(acc[m][n][1]);
          pk[2] = f2bf(acc[m][n][2]); pk[3] = f2bf(acc[m][n][3]);
          *(u16x4*)(Vt + ((long)((b2*NH + h2)*HDIM + d2)) * SS + s2) = pk;
        }
      }
    }
  } else {
    const int ccb = bn*128 + wcn*64 + lr;
#pragma unroll
    for (int m = 0; m < 8; ++m)
#pragma unroll
      for (int n = 0; n < 4; ++n)
#pragma unroll
        for (int j = 0; j < 4; ++j)
          Cf[(long)(crb + m*16 + j) * DD + (ccb + n*16)] = acc[m][n][j];
  }
}

// ------ causal flash attention: KVBLK=128, dbuf, pair-balanced ---------------
// 8 waves x 16 q-rows. vs R14: 128-key tiles halve the per-key softmax
// cross-lane cost (8 shfl + 1 rescale per 128 keys instead of per 64) and
// halve barrier count (17 iterations). PV runs in two 64-key halves reusing
// the per-wave 16x64 P buffer (LDS stays ~137 KB). Stage-at-top double
// buffer: 8 gld issued before compute; end-of-iter barrier drains them
// after ~2.5k cyc of compute (latency hidden, R12-proven pattern).
__global__ __launch_bounds__(512, 2) void attn_fwd(
    const ushort* __restrict__ Qb, const ushort* __restrict__ Kb,
    const ushort* __restrict__ Vtg, ushort* __restrict__ Ob)
{
  __shared__ ushort Ks[2][128*128]; // 2 x 32 KB, [k][d] rows 256B swizzled
  __shared__ ushort Vs[2][128*128]; // 2 x 32 KB, [d][s] rows 256B swizzled
  __shared__ ushort Ps[8*16*68];    // per-wave P [16][64], pad 68 (2-way)

  const int bid = blockIdx.x;       // 256 blocks: p(8) x bh(32)
  const int p = bid >> 5;           // 0..7
  const int bh = bid & 31;
  const int b = bh >> 4, h = bh & 15;
  const int t = threadIdx.x;
  const int lane = t & 63;
  const int wq = t >> 6;            // 0..7
  const int lr = lane & 15, lg = lane >> 4;

  // staging: K tile 2048 chunks (16B), 4/thread; V^T same. Rows 256B,
  // slot kc holds global chunk kc ^ (row&7) (low-3-bit XOR, 2-way banks).
  int koff[4], voff[4];
#pragma unroll
  for (int i = 0; i < 4; ++i) {
    int c = i*512 + t;
    int kr = c >> 4, kc = c & 15;
    koff[i] = kr*DD + ((kc ^ (kr & 7)) * 8);
    voff[i] = kr*SS + ((kc ^ (kr & 7)) * 8);   // V^T rows d: same map
  }
  const ushort* Kg = Kb + (long)(b * SS) * DD + h * HDIM;
  const ushort* Vg = Vtg + (long)(bh * HDIM) * SS;

#define STAGE(KT, BUF) do {                                     \
    const ushort* kg_ = Kg + (long)(KT) * 128 * DD;             \
    const ushort* vg_ = Vg + (KT) * 128;                        \
    _Pragma("unroll") for (int i_ = 0; i_ < 4; ++i_) {          \
      gld_lds16(kg_ + koff[i_], &Ks[BUF][i_*4096 + t*8]);       \
      gld_lds16(vg_ + voff[i_], &Vs[BUF][i_*4096 + t*8]);       \
    } } while (0)

  ushort* myP = Ps + wq * (16*68);
  const int n0 = p + 1;             // half-0 tile count (128-key tiles)
  const int TOT = 17;               // n0 + (16 - p)

  STAGE(0, 0);
  __syncthreads();                  // tile 0 resident

  int u = 0;                        // linear 128-key tile counter
  for (int half = 0; half < 2; ++half) {
    const int qt = half ? (15 - p) : p;
    const int qbase = qt * 128;
    const long rowQ = (long)(b * SS + qbase + wq * 16);
    const int ntile = qt + 1;       // keys 0 .. (qt+1)*128-1
    const int qminw = qbase + wq*16;

    bf16x8 qf[4];
#pragma unroll
    for (int c = 0; c < 4; ++c)
      qf[c] = *(const bf16x8*)(Qb + (rowQ + lr) * DD + h*HDIM + c*32 + lg*8);

    f32x4 accO[8] = {};
    float mrow[4], lrow[4];
#pragma unroll
    for (int j = 0; j < 4; ++j) { mrow[j] = -1e30f; lrow[j] = 0.f; }

    for (int kt = 0; kt < ntile; ++kt, ++u) {
      const int k0 = kt * 128;
      const int cur = u & 1;
      if (u + 1 < TOT) {            // stage next 128-key tile into other buf
        const int un = u + 1;
        const int ktn = (un < n0) ? un : un - n0;
        STAGE(ktn, cur ^ 1);
      }

      const ushort* Kc = Ks[cur];
      const ushort* Vc = Vs[cur];
      f32x4 sc[8] = {};
      __builtin_amdgcn_s_setprio(1);
#pragma unroll
      for (int n = 0; n < 8; ++n) { // S = Q K^T : 16 q-rows x 128 keys
        int r = n*16 + lr;
        int swz = (r & 7) << 4;
#pragma unroll
        for (int c = 0; c < 4; ++c) {
          bf16x8 kf = *(const bf16x8*)((const char*)Kc + ((r*256 + c*64 + lg*16) ^ swz));
          sc[n] = __builtin_amdgcn_mfma_f32_16x16x32_bf16(qf[c], kf, sc[n], 0,0,0);
        }
      }
      __builtin_amdgcn_s_setprio(0);
      if (kt == ntile - 1) {        // diagonal 128-tile: causal mask
#pragma unroll
        for (int n = 0; n < 8; ++n)
#pragma unroll
          for (int j = 0; j < 4; ++j) {
            int kpos = k0 + n*16 + lr;
            int qpos = qminw + lg*4 + j;
            if (kpos > qpos) sc[n][j] = -1e30f;
          }
      }
      float al[4];
#pragma unroll
      for (int j = 0; j < 4; ++j) { // online softmax: ONE pass per 128 keys
        float tm = fmaxf(fmaxf(fmaxf(sc[0][j], sc[1][j]), fmaxf(sc[2][j], sc[3][j])),
                         fmaxf(fmaxf(sc[4][j], sc[5][j]), fmaxf(sc[6][j], sc[7][j])));
#pragma unroll
        for (int off = 1; off < 16; off <<= 1) tm = fmaxf(tm, __shfl_xor(tm, off));
        float mn = fmaxf(mrow[j], tm);
        float a = fast_exp2(mrow[j] - mn);
        mrow[j] = mn;
        float ts = 0.f;
#pragma unroll
        for (int n = 0; n < 8; ++n) {
          float pv = fast_exp2(sc[n][j] - mn);
          sc[n][j] = pv; ts += pv;
        }
#pragma unroll
        for (int off = 1; off < 16; off <<= 1) ts += __shfl_xor(ts, off);
        lrow[j] = lrow[j] * a + ts;
        al[j] = a;
      }
#pragma unroll
      for (int dg = 0; dg < 8; ++dg) {
        f32x4 v = accO[dg];
        v[0] *= al[0]; v[1] *= al[1]; v[2] *= al[2]; v[3] *= al[3];
        accO[dg] = v;
      }
      // PV in two 64-key halves (P buffer is 16x64 per wave)
#pragma unroll
      for (int hh = 0; hh < 2; ++hh) {
#pragma unroll
        for (int n2 = 0; n2 < 4; ++n2)   // P-half -> per-wave LDS
#pragma unroll
          for (int j = 0; j < 4; ++j)
            myP[(lg*4 + j)*68 + n2*16 + lr] = f2bf(sc[hh*4 + n2][j]);
        bf16x8 pa0 = *(const bf16x8*)(myP + lr*68 + lg*8);
        bf16x8 pa1 = *(const bf16x8*)(myP + lr*68 + 32 + lg*8);
        __builtin_amdgcn_s_setprio(1);
#pragma unroll
        for (int dg = 0; dg < 8; ++dg) { // O += P_half * V_half
          int d = dg*16 + lr;
          int vswz = (d & 7) << 4;
          const char* vrow = (const char*)Vc + d*256 + hh*128;
          bf16x8 v0 = *(const bf16x8*)((const char*)Vc + ((d*256 + hh*128 + lg*16) ^ vswz));
          bf16x8 v1 = *(const bf16x8*)((const char*)Vc + ((d*256 + hh*128 + 64 + lg*16) ^ vswz));
          (void)vrow;
          accO[dg] = __builtin_amdgcn_mfma_f32_16x16x32_bf16(pa0, v0, accO[dg], 0,0,0);
          accO[dg] = __builtin_amdgcn_mfma_f32_16x16x32_bf16(pa1, v1, accO[dg], 0,0,0);
        }
        __builtin_amdgcn_s_setprio(0);
      }
      __syncthreads();              // drains next tile's loads (after compute)
    }

    float inv[4];
#pragma unroll
    for (int j = 0; j < 4; ++j) inv[j] = 1.0f / lrow[j];
    ushort* Og = Ob + rowQ * DD + h * HDIM;
#pragma unroll
    for (int dg = 0; dg < 8; ++dg)
#pragma unroll
      for (int j = 0; j < 4; ++j)
        Og[(long)(lg*4 + j) * DD + dg*16 + lr] = f2bf(accO[dg][j] * inv[j]);
  }
#undef STAGE
}

// ---------------- launch ----------------------------------------------------
extern "C" void kernel_launch(void* const* d_in, const int* in_sizes, int n_in,
                              void* d_out, int out_size, void* d_ws, size_t ws_size,
                              hipStream_t stream) {
  const float* x  = (const float*)d_in[0];
  const float* Wq = (const float*)d_in[1];
  const float* Wk = (const float*)d_in[2];
  const float* Wv = (const float*)d_in[3];
  const float* Wo = (const float*)d_in[4];

  ushort* ws  = (ushort*)d_ws;
  ushort* xb  = ws;                         // x bf16; later reused as attn-out
  ushort* wqb = ws  + (long)MM*DD;          // wq/wk/wv contiguous = fused Bt
  ushort* wkb = wqb + (long)DD*DD;
  ushort* wvb = wkb + (long)DD*DD;
  ushort* wob = wvb + (long)DD*DD;
  ushort* Qb  = wob + (long)DD*DD;
  ushort* Kb  = Qb  + (long)MM*DD;
  ushort* Vtg = Kb  + (long)MM*DD;          // V stored transposed [bh*128+d][s]
  (void)wkb; (void)wvb;

  const int CVT_BLOCKS = (MM*DD + 4*DD*DD) / 8 / 256;   // 12288
  cvt_all<<<CVT_BLOCKS, 256, 0, stream>>>(x, Wq, Wk, Wv, Wo, ws);

  gemm_tri<0><<<768, 256, 0, stream>>>(xb, wqb, Qb, Kb, Vtg, nullptr);

  attn_fwd<<<256, 512, 0, stream>>>(Qb, Kb, Vtg, xb);   // attn out -> xb

  gemm_tri<1><<<256, 256, 0, stream>>>(xb, wob, nullptr, nullptr, nullptr,
                                       (float*)d_out);
}